// Round 5
// baseline (232.853 us; speedup 1.0000x reference)
//
#include <hip/hip_runtime.h>
#include <hip/hip_bf16.h>

// B=128, S=256, E=768, C=4; M = B*S = 32768.
// R4 kernel + K2 rewritten with a 128x256 block tile (grid 3x256):
//  - halves segF8 re-fetch (A-panel read 6x -> 3x)
//  - halves total barrier count per FLOP
//  - 8 MFMA : 12 ds_read_b128 per wave per K-step (was 4:8)
// Everything else identical to R4 (elision in prep-conv and K2/K3 m-blocks,
// fused W3 GEMV in K3, shfl-scan head).
// 4 launches: prep | K2 (fp8-MX MFMA) | K3 (fused W3 GEMV epilogue) | head.

typedef __attribute__((ext_vector_type(8))) short short8;
typedef __attribute__((ext_vector_type(8))) unsigned short ushort8;
typedef __attribute__((ext_vector_type(16))) float f32x16;
typedef __attribute__((ext_vector_type(8))) int i32x8;
typedef __attribute__((ext_vector_type(4))) int i32x4;

__device__ __forceinline__ unsigned short f2bf(float f) {
    union { float f; unsigned int u; } c; c.f = f;
    unsigned int u = c.u;
    unsigned int r = (u + 0x7FFFu + ((u >> 16) & 1u)) >> 16;  // RNE
    return (unsigned short)r;
}
__device__ __forceinline__ float bf2f(unsigned short u) {
    union { unsigned int u; float f; } c; c.u = ((unsigned int)u) << 16;
    return c.f;
}
__device__ __forceinline__ float gelu_fast(float x) {
    float x2 = x * x;
    float y2 = 1.5957691216057308f * (x + 0.044715f * x2 * x);
    float e = __expf(y2);
    float t = 1.0f - 2.0f * __builtin_amdgcn_rcpf(e + 1.0f);
    return 0.5f * x * (1.0f + t);
}

typedef const __attribute__((address_space(1))) void* gas_t;
typedef __attribute__((address_space(3))) void* las_t;
__device__ __forceinline__ void g2l16(const void* g, void* l) {
    __builtin_amdgcn_global_load_lds((gas_t)g, (las_t)l, 16, 0, 0);
}

// pack 4 floats -> 4 fp8 e4m3 bytes (RNE, saturating)
__device__ __forceinline__ unsigned int f4_to_fp8x4(float a, float b, float c, float d) {
    int lo = __builtin_amdgcn_cvt_pk_fp8_f32(a, b, 0, 0);
    return (unsigned int)__builtin_amdgcn_cvt_pk_fp8_f32(c, d, lo, 1);
}
__device__ __forceinline__ unsigned char f_to_fp8(float a) {
    return (unsigned char)(__builtin_amdgcn_cvt_pk_fp8_f32(a, a, 0, 0) & 0xFF);
}

// ---------------- fused prep kernel ----------------
#define PREP_Q    96
#define PREP_TR1E 240
#define PREP_TR2E 312
#define PREP_END  12600

__global__ __launch_bounds__(256) void prep_kernel(
    const float* __restrict__ segments, unsigned char* __restrict__ segF8,
    const float* __restrict__ W1, unsigned char* __restrict__ W1t8,
    const float* __restrict__ W2, unsigned char* __restrict__ W2t8,
    const float* __restrict__ questions, float* __restrict__ qW1p,
    const int* __restrict__ nseg)
{
    __shared__ __align__(16) char sh[34816];
    const int bid = blockIdx.x, tid = threadIdx.x;

    if (bid < PREP_Q) {
        // q-GEMM: questions[128,768] @ W1[:768] -> qW1p[4][128][768]
        // 96 blocks = 4 ksplits x 2 m-tiles(64) x 12 n-tiles(64).
        float (*As)[68] = (float(*)[68])sh;               // [k][m] transposed
        float (*Bs)[68] = (float(*)[68])(sh + 17408);     // [k][n]
        const int s = bid / 24, rem = bid % 24;
        const int n0 = (rem % 12) * 64, m0 = (rem / 12) * 64;
        const int tn = tid & 15, tm = tid >> 4;
        const int lr = tid >> 2;
        const int lc = tid & 3;
        float acc[4][4] = {};
        const int kbeg = s * 192;
        for (int kc = kbeg; kc < kbeg + 192; kc += 64) {
            const float* ap = questions + (size_t)(m0 + lr) * 768 + kc;
            #pragma unroll
            for (int p = 0; p < 4; p++) {
                int kk = lc * 4 + 16 * p;
                float4 v = *(const float4*)(ap + kk);
                As[kk + 0][lr] = v.x; As[kk + 1][lr] = v.y;
                As[kk + 2][lr] = v.z; As[kk + 3][lr] = v.w;
            }
            const float* bp = W1 + (size_t)(kc + lr) * 768 + n0 + lc * 16;
            #pragma unroll
            for (int p = 0; p < 4; p++)
                *(float4*)&Bs[lr][lc * 16 + 4 * p] = *(const float4*)(bp + 4 * p);
            __syncthreads();
            #pragma unroll 2
            for (int k = 0; k < 64; k++) {
                float4 a = *(const float4*)&As[k][tm * 4];
                float4 b = *(const float4*)&Bs[k][tn * 4];
                float ar4[4] = {a.x, a.y, a.z, a.w};
                float br4[4] = {b.x, b.y, b.z, b.w};
                #pragma unroll
                for (int i = 0; i < 4; i++)
                    #pragma unroll
                    for (int j = 0; j < 4; j++)
                        acc[i][j] += ar4[i] * br4[j];
            }
            __syncthreads();
        }
        float* outp = qW1p + (size_t)s * 128 * 768;
        #pragma unroll
        for (int i = 0; i < 4; i++) {
            int row = m0 + tm * 4 + i;
            *(float4*)&outp[(size_t)row * 768 + n0 + tn * 4] =
                make_float4(acc[i][0], acc[i][1], acc[i][2], acc[i][3]);
        }
        return;
    }

    if (bid < PREP_TR2E) {
        // transpose 64x64 tile -> fp8 bytes
        const float* in; unsigned char* outp; int R, C, bx, by;
        if (bid < PREP_TR1E) {
            int idx = bid - PREP_Q; bx = idx % 12; by = idx / 12;
            in = W1 + 768 * 768; outp = W1t8; R = 768; C = 768;
        } else {
            int idx = bid - PREP_TR1E; bx = idx % 6; by = idx / 6;
            in = W2; outp = W2t8; R = 768; C = 384;
        }
        float (*t)[65] = (float(*)[65])sh;
        int r0 = by * 64, c0 = bx * 64;
        int tx = tid & 63, ty = tid >> 6;
        #pragma unroll
        for (int p = 0; p < 16; p++) {
            int row = ty * 16 + p;
            t[row][tx] = in[(size_t)(r0 + row) * C + c0 + tx];
        }
        __syncthreads();
        #pragma unroll
        for (int p = 0; p < 16; p++) {
            int orow = ty * 16 + p;
            outp[(size_t)(c0 + orow) * R + r0 + tx] = f_to_fp8(t[tx][orow]);
        }
        return;
    }

    // conv: segments fp32 -> segF8 fp8 (8 elems/thread, 2048 elems/block).
    // Skip blocks whose rows are all masked (row_in_bag >= nseg[bag]).
    {
        int cb = bid - PREP_TR2E;
        int row0 = (cb * 2048) / 768;
        if ((row0 & 255) >= nseg[row0 >> 8]) return;
        long i = (long)cb * 256 + tid;
        const float4* in = (const float4*)segments;
        float4 a = in[2 * i], b = in[2 * i + 1];
        unsigned int lo = f4_to_fp8x4(a.x, a.y, a.z, a.w);
        unsigned int hi = f4_to_fp8x4(b.x, b.y, b.z, b.w);
        *(uint2*)(segF8 + i * 8) = make_uint2(lo, hi);
    }
}

// ---------------- K2: fp8 MX MFMA GEMM, 128x256 block tile ----------------
// H1f8[32768,768] = fp8(gelu(segF8 @ W1t8^T + b1 + sum_s qW1p[s][bag]))
// grid (3, 256); 4 waves, each 128 rows x 64 cols = 4x2 of 32x32x64.
__global__ __launch_bounds__(256) void mfma_gemm_f8_k2(
    const unsigned char* __restrict__ A8,    // [M,768] fp8
    const unsigned char* __restrict__ Bt8,   // [768,768] fp8 (N rows, K cols)
    const float* __restrict__ bias,          // [768]
    const float* __restrict__ rowAdd,        // [4][128][768]
    unsigned char* __restrict__ Cout,        // [M,768] fp8
    const int* __restrict__ nseg)
{
    const int K = 768;
    __shared__ __align__(16) unsigned char smem8[32768]; // 24KB staging / 32KB epilogue
    unsigned char* As = smem8;             // [128][64B] swizzled (8KB)
    unsigned char* Bs = smem8 + 8192;      // [256][64B] swizzled (16KB)
    const int tid = threadIdx.x;
    const int wave = tid >> 6, lane = tid & 63;
    const int m0 = blockIdx.y * 128, n0 = blockIdx.x * 256;

    if (nseg[m0 >> 8] <= (m0 & 255)) return;

    f32x16 acc[4][2] = {};

    const int srow = tid >> 2;                       // 0..63
    const int schunk = (tid & 3) ^ ((srow >> 1) & 3);
    const unsigned char* Ag = A8 + (size_t)(m0 + srow) * K + schunk * 16;
    const unsigned char* Bg = Bt8 + (size_t)(n0 + srow) * K + schunk * 16;
    unsigned char* Al = As + tid * 16;
    unsigned char* Bl = Bs + tid * 16;
    const int fm = lane & 31, fq = lane >> 5;

    for (int k0 = 0; k0 < K; k0 += 64) {
        g2l16(Ag + k0, Al);
        g2l16(Ag + (size_t)64 * K + k0, Al + 4096);
        g2l16(Bg + k0, Bl);
        g2l16(Bg + (size_t)64 * K + k0, Bl + 4096);
        g2l16(Bg + (size_t)128 * K + k0, Bl + 8192);
        g2l16(Bg + (size_t)192 * K + k0, Bl + 12288);
        __syncthreads();

        i32x8 av[4], bv[2];
        #pragma unroll
        for (int i = 0; i < 4; i++) {
            int rw = i * 32 + fm, key = (rw >> 1) & 3;
            i32x4 lo = *(const i32x4*)&As[rw * 64 + (((fq << 1) | 0) ^ key) * 16];
            i32x4 hi = *(const i32x4*)&As[rw * 64 + (((fq << 1) | 1) ^ key) * 16];
            av[i][0] = lo[0]; av[i][1] = lo[1]; av[i][2] = lo[2]; av[i][3] = lo[3];
            av[i][4] = hi[0]; av[i][5] = hi[1]; av[i][6] = hi[2]; av[i][7] = hi[3];
        }
        #pragma unroll
        for (int j = 0; j < 2; j++) {
            int rw = wave * 64 + j * 32 + fm, key = (rw >> 1) & 3;
            i32x4 lo = *(const i32x4*)&Bs[rw * 64 + (((fq << 1) | 0) ^ key) * 16];
            i32x4 hi = *(const i32x4*)&Bs[rw * 64 + (((fq << 1) | 1) ^ key) * 16];
            bv[j][0] = lo[0]; bv[j][1] = lo[1]; bv[j][2] = lo[2]; bv[j][3] = lo[3];
            bv[j][4] = hi[0]; bv[j][5] = hi[1]; bv[j][6] = hi[2]; bv[j][7] = hi[3];
        }
        #pragma unroll
        for (int i = 0; i < 4; i++)
            #pragma unroll
            for (int j = 0; j < 2; j++)
                acc[i][j] = __builtin_amdgcn_mfma_scale_f32_32x32x64_f8f6f4(
                    av[i], bv[j], acc[i][j], 0, 0, 0, 127, 0, 127);
        __syncthreads();
    }

    // Epilogue: gelu + fp8 into 32KB LDS, then 16B-coalesced store.
    #pragma unroll
    for (int j = 0; j < 2; j++) {
        int coll = wave * 64 + j * 32 + fm;      // 0..255
        int col = n0 + coll;
        float add = bias[col];
        const float* radd = rowAdd + (size_t)(m0 >> 8) * 768 + col;
        add += radd[0] + radd[98304] + radd[2 * 98304] + radd[3 * 98304];
        #pragma unroll
        for (int i = 0; i < 4; i++) {
            int rbase = i * 32 + 4 * fq;
            #pragma unroll
            for (int reg = 0; reg < 16; reg++) {
                int rowl = rbase + (reg & 3) + 8 * (reg >> 2);
                float v = gelu_fast(acc[i][j][reg] + add);
                smem8[rowl * 256 + coll] = f_to_fp8(v);
            }
        }
    }
    __syncthreads();
    #pragma unroll
    for (int it = 0; it < 8; it++) {
        int idx = it * 256 + tid;
        int r = idx >> 4, cc = (idx & 15) * 16;
        *(uint4*)&Cout[(size_t)(m0 + r) * 768 + n0 + cc] =
            *(const uint4*)&smem8[r * 256 + cc];
    }
}

// ---------------- K3: fp8 MX MFMA GEMM + fused W3 GEMV ----------------
// 128x128 block, 4 waves, wave 64x64 = 2x2 of 32x32x64 (unit scales).
__global__ __launch_bounds__(256) void mfma_gemm_f8_k3(
    const unsigned char* __restrict__ A8,    // [M,768] fp8
    const unsigned char* __restrict__ Bt8,   // [384,768] fp8
    const float* __restrict__ bias,          // [384]
    float* __restrict__ CoutV,               // [3][32768][4] f32 partial preds
    int K,
    const float* __restrict__ W3p,           // [384][4]
    const int* __restrict__ nseg)
{
    __shared__ __align__(16) unsigned char smem8[32768 + 2048];
    unsigned char* As = smem8;
    unsigned char* Bs = smem8 + 8192;
    const int tid = threadIdx.x;
    const int wave = tid >> 6, lane = tid & 63;
    const int m0 = blockIdx.y * 128, n0 = blockIdx.x * 128;

    if (nseg[m0 >> 8] <= (m0 & 255)) return;

    const int wm = (wave & 1) * 64, wn = (wave >> 1) * 64;

    if (tid < 128)
        ((float4*)(smem8 + 32768))[tid] = ((const float4*)W3p)[n0 + tid];

    f32x16 acc[2][2] = {};

    const int srow = tid >> 2;
    const int schunk = (tid & 3) ^ ((srow >> 1) & 3);
    const unsigned char* Ag = A8 + (size_t)(m0 + srow) * K + schunk * 16;
    const unsigned char* Bg = Bt8 + (size_t)(n0 + srow) * K + schunk * 16;
    unsigned char* Al = As + tid * 16;
    unsigned char* Bl = Bs + tid * 16;

    const int fm = lane & 31, fq = lane >> 5;

    for (int k0 = 0; k0 < K; k0 += 64) {
        g2l16(Ag + k0, Al);
        g2l16(Ag + (size_t)64 * K + k0, Al + 4096);
        g2l16(Bg + k0, Bl);
        g2l16(Bg + (size_t)64 * K + k0, Bl + 4096);
        __syncthreads();

        i32x8 av[2], bv[2];
        #pragma unroll
        for (int i = 0; i < 2; i++) {
            int rw = wm + i * 32 + fm, key = (rw >> 1) & 3;
            i32x4 lo = *(const i32x4*)&As[rw * 64 + (((fq << 1) | 0) ^ key) * 16];
            i32x4 hi = *(const i32x4*)&As[rw * 64 + (((fq << 1) | 1) ^ key) * 16];
            av[i][0] = lo[0]; av[i][1] = lo[1]; av[i][2] = lo[2]; av[i][3] = lo[3];
            av[i][4] = hi[0]; av[i][5] = hi[1]; av[i][6] = hi[2]; av[i][7] = hi[3];
        }
        #pragma unroll
        for (int j = 0; j < 2; j++) {
            int rw = wn + j * 32 + fm, key = (rw >> 1) & 3;
            i32x4 lo = *(const i32x4*)&Bs[rw * 64 + (((fq << 1) | 0) ^ key) * 16];
            i32x4 hi = *(const i32x4*)&Bs[rw * 64 + (((fq << 1) | 1) ^ key) * 16];
            bv[j][0] = lo[0]; bv[j][1] = lo[1]; bv[j][2] = lo[2]; bv[j][3] = lo[3];
            bv[j][4] = hi[0]; bv[j][5] = hi[1]; bv[j][6] = hi[2]; bv[j][7] = hi[3];
        }
        #pragma unroll
        for (int i = 0; i < 2; i++)
            #pragma unroll
            for (int j = 0; j < 2; j++)
                acc[i][j] = __builtin_amdgcn_mfma_scale_f32_32x32x64_f8f6f4(
                    av[i], bv[j], acc[i][j], 0, 0, 0, 127, 0, 127);
        __syncthreads();
    }

    // Epilogue: gelu -> bf16 tile in LDS
    #pragma unroll
    for (int j = 0; j < 2; j++) {
        int coll = wn + j * 32 + fm;
        int col = n0 + coll;
        float add = bias[col];
        #pragma unroll
        for (int i = 0; i < 2; i++) {
            int rbase = wm + i * 32 + 4 * fq;
            #pragma unroll
            for (int reg = 0; reg < 16; reg++) {
                int rowl = rbase + (reg & 3) + 8 * (reg >> 2);
                float v = gelu_fast(acc[i][j][reg] + add);
                ((unsigned short*)smem8)[rowl * 128 + coll] = f2bf(v);
            }
        }
    }
    __syncthreads();
    {
        // per-row GEMV with the W3 chunk: 2 threads/row, 64 cols each.
        const float4* w3sh = (const float4*)(smem8 + 32768);
        const unsigned short* tile = (const unsigned short*)smem8;
        int r = tid >> 1, ch = tid & 1;
        const unsigned short* rowp = tile + r * 128 + ch * 64;
        float4 a = make_float4(0.f, 0.f, 0.f, 0.f);
        #pragma unroll
        for (int k = 0; k < 8; k++) {
            int kk = k ^ (r & 7);
            ushort8 u = *(const ushort8*)(rowp + kk * 8);
            #pragma unroll
            for (int jj = 0; jj < 8; jj++) {
                float h = bf2f(u[jj]);
                float4 wv2 = w3sh[ch * 64 + kk * 8 + jj];
                a.x += h * wv2.x; a.y += h * wv2.y;
                a.z += h * wv2.z; a.w += h * wv2.w;
            }
        }
        a.x += __shfl_xor(a.x, 1); a.y += __shfl_xor(a.y, 1);
        a.z += __shfl_xor(a.z, 1); a.w += __shfl_xor(a.w, 1);
        if (ch == 0)
            ((float4*)CoutV)[(size_t)blockIdx.x * 32768 + m0 + r] = a;
    }
}

// ---------------- head: softmax + aggregation over partial preds ----------------
__device__ __forceinline__ float4 f4mul(float4 a, float4 b) {
    return make_float4(a.x * b.x, a.y * b.y, a.z * b.z, a.w * b.w);
}

__device__ __forceinline__ float4 block_scan_prod(float4 v, int lane, int wv,
                                                  float4* wtot) {
    #pragma unroll
    for (int off = 1; off < 64; off <<= 1) {
        float4 t;
        t.x = __shfl_up(v.x, off); t.y = __shfl_up(v.y, off);
        t.z = __shfl_up(v.z, off); t.w = __shfl_up(v.w, off);
        if (lane >= off) v = f4mul(v, t);
    }
    if (lane == 63) wtot[wv] = v;
    __syncthreads();
    float4 pre = make_float4(1.f, 1.f, 1.f, 1.f);
    #pragma unroll
    for (int w = 0; w < 3; w++)
        if (w < wv) pre = f4mul(pre, wtot[w]);
    __syncthreads();
    return f4mul(pre, v);
}

__global__ __launch_bounds__(256) void head_kernel(
    const float* __restrict__ pp,   // [3][32768][4] partial preds
    const float* __restrict__ b3,
    const int* __restrict__ nseg,
    float* __restrict__ out)
{
    __shared__ float4 xbuf[256];
    __shared__ float4 wtot[4];
    const int b = blockIdx.x, tid = threadIdx.x;
    const int lane = tid & 63, wv = tid >> 6;
    const float4 ones = make_float4(1.f, 1.f, 1.f, 1.f);

    const float4* ppv = (const float4*)pp;
    size_t row = (size_t)b * 256 + tid;
    float4 a0 = ppv[row], a1 = ppv[row + 32768], a2 = ppv[row + 65536];
    float4 acc = make_float4(a0.x + a1.x + a2.x + b3[0],
                             a0.y + a1.y + a2.y + b3[1],
                             a0.z + a1.z + a2.z + b3[2],
                             a0.w + a1.w + a2.w + b3[3]);
    float m = fmaxf(fmaxf(acc.x, acc.y), fmaxf(acc.z, acc.w));
    float e0 = __expf(acc.x - m), e1 = __expf(acc.y - m),
          e2 = __expf(acc.z - m), e3 = __expf(acc.w - m);
    float inv = 1.0f / (e0 + e1 + e2 + e3);
    float4 p = make_float4(e0 * inv, e1 * inv, e2 * inv, e3 * inv);

    const int n = nseg[b];
    bool msk = tid < n;
    float s1 = p.x, s2 = s1 + p.y, s3 = s2 + p.z;
    float4 sm = msk ? make_float4(0.f, s1, s2, s3) : ones;

    float4 isc = block_scan_prod(sm, lane, wv, wtot);
    xbuf[tid] = isc;
    __syncthreads();
    float4 pfx = (tid > 0) ? xbuf[tid - 1] : ones;
    __syncthreads();

    xbuf[255 - tid] = sm;
    __syncthreads();
    float4 rsm = xbuf[tid];
    __syncthreads();
    float4 risc = block_scan_prod(rsm, lane, wv, wtot);
    xbuf[tid] = risc;
    __syncthreads();
    float4 sfx = (tid < 255) ? xbuf[254 - tid] : ones;
    __syncthreads();

    float4 L = f4mul(pfx, sfx);
    float4 cpL = block_scan_prod(L, lane, wv, wtot);

    float4 term = msk ? f4mul(p, cpL) : make_float4(0.f, 0.f, 0.f, 0.f);
    float4 pm = msk ? p : ones;
    #pragma unroll
    for (int off = 32; off > 0; off >>= 1) {
        term.x += __shfl_xor(term.x, off); term.y += __shfl_xor(term.y, off);
        term.z += __shfl_xor(term.z, off); term.w += __shfl_xor(term.w, off);
        pm.x *= __shfl_xor(pm.x, off); pm.y *= __shfl_xor(pm.y, off);
        pm.z *= __shfl_xor(pm.z, off); pm.w *= __shfl_xor(pm.w, off);
    }
    if (lane == 0) { xbuf[wv] = term; xbuf[4 + wv] = pm; }
    __syncthreads();
    if (tid == 0) {
        float4 st = make_float4(0.f, 0.f, 0.f, 0.f);
        float4 pr = ones;
        #pragma unroll
        for (int w = 0; w < 4; w++) {
            float4 t = xbuf[w], q = xbuf[4 + w];
            st.x += t.x; st.y += t.y; st.z += t.z; st.w += t.w;
            pr = f4mul(pr, q);
        }
        ((float4*)out)[b] = make_float4(0.25f * st.x + pr.x,
                                        0.25f * st.y + pr.y,
                                        0.25f * st.z + pr.z,
                                        0.25f * st.w + pr.w);
    }
}

extern "C" void kernel_launch(void* const* d_in, const int* in_sizes, int n_in,
                              void* d_out, int out_size, void* d_ws, size_t ws_size,
                              hipStream_t stream) {
    (void)in_sizes; (void)n_in; (void)out_size; (void)ws_size;
    const float* questions = (const float*)d_in[0];
    const float* segments  = (const float*)d_in[1];
    const float* W1 = (const float*)d_in[2];
    const float* b1 = (const float*)d_in[3];
    const float* W2 = (const float*)d_in[4];
    const float* b2 = (const float*)d_in[5];
    const float* W3 = (const float*)d_in[6];
    const float* b3 = (const float*)d_in[7];
    const int*  nseg = (const int*)d_in[8];
    float* out = (float*)d_out;

    char* w = (char*)d_ws;
    float* qW1p = (float*)w;                   w += (size_t)4 * 128 * 768 * 4;
    unsigned char*  W1t8 = (unsigned char*)w;  w += (size_t)768 * 768;
    unsigned char*  W2t8 = (unsigned char*)w;  w += (size_t)384 * 768;
    unsigned char*  segF8 = (unsigned char*)w; w += (size_t)32768 * 768;
    unsigned char*  H1f8 = (unsigned char*)w;  w += (size_t)32768 * 768;
    float* ppreds = (float*)w;                 w += (size_t)3 * 32768 * 4 * 4;

    prep_kernel<<<PREP_END, 256, 0, stream>>>(
        segments, segF8, W1, W1t8, W2, W2t8, questions, qW1p, nseg);
    // K2 (fp8 -> fp8): 128x256 tile, grid (n=3, m=256)
    mfma_gemm_f8_k2<<<dim3(3, 256), 256, 0, stream>>>(
        segF8, W1t8, b1, qW1p, H1f8, nseg);
    // K3 (fp8 -> fused W3 partial preds): grid (n=3, m=256)
    mfma_gemm_f8_k3<<<dim3(3, 256), 256, 0, stream>>>(
        H1f8, W2t8, b2, ppreds, 768, W3, nseg);
    head_kernel<<<128, 256, 0, stream>>>(ppreds, b3, nseg, out);
}